// Round 1
// baseline (413.432 us; speedup 1.0000x reference)
//
#include <hip/hip_runtime.h>
#include <math.h>

typedef _Float16 f16x8 __attribute__((ext_vector_type(8)));
typedef _Float16 f16x4 __attribute__((ext_vector_type(4)));
typedef float f32x4 __attribute__((ext_vector_type(4)));

#define TLEN 512
#define BT 16
#define MFMA(a,b,c) __builtin_amdgcn_mfma_f32_16x16x32_f16(a,b,c,0,0,0)
#define LOG2E 1.44269504f

// Workgroup barrier WITHOUT the vmcnt(0)/expcnt(0) drain __syncthreads emits.
// Only LDS data crosses the barrier (lgkmcnt(0) orders ds_writes); global
// loads are wave-private (compiler inserts vmcnt waits at use); out-stores
// are never re-read in-kernel.
__device__ __forceinline__ void bar_lds() {
    asm volatile("s_waitcnt lgkmcnt(0)\n\ts_barrier" ::: "memory");
}

__device__ __forceinline__ float sigmoid2_f(float x) {
    return __builtin_amdgcn_rcpf(1.f + __builtin_amdgcn_exp2f(-LOG2E * x));
}
__device__ __forceinline__ float tanh2_f(float x) {
    float t = __builtin_amdgcn_rcpf(1.f + __builtin_amdgcn_exp2f(2.f * LOG2E * x));
    return fmaf(-2.f, t, 1.f);
}

// R11: 8-wave producer/helper split (512 thr, 256 blocks, 2 waves/SIMD).
// Waves 0-3 ("A"): the true recurrence — 18 state MFMAs + gates + h~ publish.
// Waves 4-7 ("B"): h-independent work ONE STEP AHEAD — 9 x-path MFMAs,
// decay exp2 (two steps ahead), x prefetch/staging, output combine —
// delivered via double-buffered EXC. One bar_lds per substep.
// EXC[b] (written by B at iter t into b=(t+1)&1) = {x(t+1) R/Z/Ni, dec(t+2)}.
// A at iter t reads EXC[t&1] = {x(t), dec(t+1)}; disjoint buffers per window.
__global__ __launch_bounds__(512, 2) void grut1_kernel(
    const float* __restrict__ X, const float* __restrict__ dtp,
    const float* __restrict__ w_ih, const float* __restrict__ w_hh,
    const float* __restrict__ b_ih, const float* __restrict__ b_hh,
    const float* __restrict__ w_dt, const float* __restrict__ b_dt,
    const float* __restrict__ w_out, const float* __restrict__ b_out,
    float* __restrict__ out)
{
    __shared__ __align__(16) _Float16 Bs[4096];    // [phase2][plane2][kt2][512] h~ hi/lo
    __shared__ __align__(16) _Float16 Bx[16384];   // [par2][t8][plane2][512] x hi/lo (B-private)
    __shared__ __align__(16) float PPc[512];       // [Awave4][b16][t8]
    __shared__ __align__(16) float EXC[2][4][4][64][4]; // [buf][pair][R,Z,Ni,dec][lane][r]

    const int tid = threadIdx.x;
    const int w = tid >> 6;
    const int l = tid & 63;
    const int n16 = l & 15;
    const int quad = l >> 4;
    const int p = w & 3;
    const bool isA = (w < 4);
    const int tid2 = tid - 256;
    const int b0g = blockIdx.x * BT;
    const int hq0 = p * 16 + quad * 4;

    // B-state publish offset (halfwords): k_local = 16(p&1)+4q+r, contiguous r
    const int bsoff = (p >> 1) * 512
                    + (((2 * (p & 1) + (quad >> 1)) * 16) + n16) * 8
                    + (quad & 1) * 4;

    const float bout = b_out[0];
    const f32x4 zero4 = {0.f, 0.f, 0.f, 0.f};
    const float* dtb = dtp + (size_t)(b0g + n16) * TLEN;

    // ---- persistent per-role state ----
    f16x8 Ah[3][2], Al[3][2];            // A: w_hh hi/lo frags
    f32x4 seedR = zero4, seedZ = zero4, biasNhV = zero4;
    float wout4[4];
    f32x4 dcur = zero4;                  // A: dec(t), refilled from EXC each iter
    float hreg[4] = {0.f, 0.f, 0.f, 0.f};
    float htl[4];                        // A: h~(t), live across the barrier
    float pbuf[8];

    f16x8 Axh[3], Axl[3];                // B: w_ih hi/lo frags
    f32x4 seedNi = zero4;
    float wdt4[4], bdt4[4];              // B: decay params
    float4 dtc0, dtc1, dtn0, dtn1;       // B: dt pipeline
    int xg2[3], xw2[3], xv2[3];          // B: x staging maps
    float xst[3];

    if (isA) {
#pragma unroll
        for (int r = 0; r < 4; ++r) {
            int j = hq0 + r;
            wout4[r] = w_out[j];
            seedR[r] = b_ih[j] + b_hh[j];
            seedZ[r] = b_ih[64 + j] + b_hh[64 + j];
            biasNhV[r] = b_hh[128 + j];
        }
#pragma unroll
        for (int g = 0; g < 3; ++g) {
            const int row = g * 64 + p * 16 + n16;
#pragma unroll
            for (int kt = 0; kt < 2; ++kt) {
                const float* src = w_hh + row * 64 + kt * 32 + quad * 8;
                f16x8 hi, lo;
#pragma unroll
                for (int i = 0; i < 8; ++i) {
                    float v = src[i];
                    _Float16 h = (_Float16)v;
                    hi[i] = h;
                    lo[i] = (_Float16)(v - (float)h);
                }
                Ah[g][kt] = hi;
                Al[g][kt] = lo;
            }
        }
        // dec(0) self-computed once; dec(t>=1) arrives via EXC from B
        float dt0 = dtb[0];
#pragma unroll
        for (int r = 0; r < 4; ++r) {
            int j = hq0 + r;
            dcur[r] = __builtin_amdgcn_exp2f(
                -LOG2E * fmaxf(fmaf(dt0, w_dt[j], b_dt[j]), 0.f));
        }
    } else {
#pragma unroll
        for (int r = 0; r < 4; ++r) {
            int j = hq0 + r;
            seedNi[r] = b_ih[128 + j];
            wdt4[r] = w_dt[j];
            bdt4[r] = b_dt[j];
        }
#pragma unroll
        for (int g = 0; g < 3; ++g) {
            const int row = g * 64 + p * 16 + n16;
            f16x8 hi, lo;
#pragma unroll
            for (int i = 0; i < 8; ++i) {
                float v = (quad == 0 && i < 5) ? w_ih[row * 5 + i] : 0.f;
                _Float16 h = (_Float16)v;
                hi[i] = h;
                lo[i] = (_Float16)(v - (float)h);
            }
            Axh[g] = hi;
            Axl[g] = lo;
        }
        // x staging map over 256 B-threads: v -> b = v/40, tt = (v%40)/5, f = v%5
#pragma unroll
        for (int i = 0; i < 3; ++i) {
            int v = tid2 + i * 256;
            xv2[i] = (v < 640);
            int vv = xv2[i] ? v : 0;
            int b = vv / 40;
            int rem = vv - b * 40;
            int tt = rem / 5;
            int f = rem - tt * 5;
            xg2[i] = (b0g + b) * (TLEN * 5) + rem;
            xw2[i] = tt * 1024 + b * 8 + f;
        }
        dtc0 = *(const float4*)(dtb);
        dtc1 = *(const float4*)(dtb + 4);
        // zero Bx (unused K slots must be 0.0f16)
        float4 z4 = make_float4(0.f, 0.f, 0.f, 0.f);
        float4* p4 = (float4*)Bx;
#pragma unroll
        for (int i = 0; i < 8; ++i) p4[tid2 + i * 256] = z4;
    }
    __syncthreads();
    if (!isA) {
        // stage chunk-0 x
#pragma unroll
        for (int i = 0; i < 3; ++i) if (xv2[i]) {
            float v = X[xg2[i]];
            _Float16 h = (_Float16)v;
            Bx[xw2[i]] = h;
            Bx[512 + xw2[i]] = (_Float16)(v - (float)h);
        }
    }
    __syncthreads();
    if (!isA) {
        // prologue: EXC[0] = { x(0), dec(1) }; ordered before A's read by bar(0)
        f16x8 Bxh = *(const f16x8*)&Bx[l * 8];
        f16x8 Bxl = *(const f16x8*)&Bx[512 + l * 8];
        f32x4 Rx  = MFMA(Axh[0], Bxh, zero4);
        f32x4 Zx  = MFMA(Axh[1], Bxh, zero4);
        f32x4 Nix = MFMA(Axh[2], Bxh, seedNi);
        Rx  = MFMA(Axl[0], Bxh, Rx);
        Zx  = MFMA(Axl[1], Bxh, Zx);
        Nix = MFMA(Axl[2], Bxh, Nix);
        Rx  = MFMA(Axh[0], Bxl, Rx);
        Zx  = MFMA(Axh[1], Bxl, Zx);
        Nix = MFMA(Axh[2], Bxl, Nix);
        f32x4 decv;
#pragma unroll
        for (int r = 0; r < 4; ++r)
            decv[r] = __builtin_amdgcn_exp2f(
                -LOG2E * fmaxf(fmaf(dtc0.y, wdt4[r], bdt4[r]), 0.f));
        *(f32x4*)&EXC[0][p][0][l][0] = Rx;
        *(f32x4*)&EXC[0][p][1][l][0] = Zx;
        *(f32x4*)&EXC[0][p][2][l][0] = Nix;
        *(f32x4*)&EXC[0][p][3][l][0] = decv;
    }

#pragma unroll 1
    for (int tb = 0; tb < TLEN; tb += 8) {
        const int npar = (((tb >> 3) & 1) ^ 1);
#pragma unroll
        for (int sub = 0; sub < 8; ++sub) {
            const int pB = (sub & 1) * 2048;
            if (isA) {
                // publish h~(t) = dec(t) * h(t-1), fp16 hi/lo (all 4 r)
                f16x4 vh, vl;
#pragma unroll
                for (int r = 0; r < 4; ++r) {
                    float v = dcur[r] * hreg[r];
                    htl[r] = v;
                    _Float16 h = (_Float16)v;
                    vh[r] = h;
                    vl[r] = (_Float16)(v - (float)h);
                }
                *(f16x4*)&Bs[pB + bsoff] = vh;
                *(f16x4*)&Bs[pB + 1024 + bsoff] = vl;
            }
            bar_lds();   // the single per-substep barrier
            if (isA) {
                const int eb = sub & 1;
                f32x4 RxV  = *(const f32x4*)&EXC[eb][p][0][l][0];
                f32x4 ZxV  = *(const f32x4*)&EXC[eb][p][1][l][0];
                f32x4 NiV  = *(const f32x4*)&EXC[eb][p][2][l][0];
                f32x4 decN = *(const f32x4*)&EXC[eb][p][3][l][0];
                f16x8 Bh0 = *(const f16x8*)&Bs[pB + l * 8];
                f16x8 Bl0 = *(const f16x8*)&Bs[pB + 1024 + l * 8];
                f16x8 Bh1 = *(const f16x8*)&Bs[pB + 512 + l * 8];
                f16x8 Bl1 = *(const f16x8*)&Bs[pB + 1536 + l * 8];
                __builtin_amdgcn_s_setprio(1);
                // 18 state MFMAs, 3 chains of 6 (R, Z, Nh), bias-seeded
                f32x4 aR  = MFMA(Ah[0][0], Bh0, seedR);
                f32x4 aZ  = MFMA(Ah[1][0], Bh0, seedZ);
                f32x4 aNh = MFMA(Ah[2][0], Bh0, biasNhV);
                aR  = MFMA(Al[0][0], Bh0, aR);
                aZ  = MFMA(Al[1][0], Bh0, aZ);
                aNh = MFMA(Al[2][0], Bh0, aNh);
                aR  = MFMA(Ah[0][0], Bl0, aR);
                aZ  = MFMA(Ah[1][0], Bl0, aZ);
                aNh = MFMA(Ah[2][0], Bl0, aNh);
                aR  = MFMA(Ah[0][1], Bh1, aR);
                aZ  = MFMA(Ah[1][1], Bh1, aZ);
                aNh = MFMA(Ah[2][1], Bh1, aNh);
                aR  = MFMA(Al[0][1], Bh1, aR);
                aZ  = MFMA(Al[1][1], Bh1, aZ);
                aNh = MFMA(Al[2][1], Bh1, aNh);
                aR  = MFMA(Ah[0][1], Bl1, aR);
                aZ  = MFMA(Ah[1][1], Bl1, aZ);
                aNh = MFMA(Ah[2][1], Bl1, aNh);
                // gates + h update + pred
                float pp = 0.f;
#pragma unroll
                for (int r = 0; r < 4; ++r) {
                    float rr = sigmoid2_f(aR[r] + RxV[r]);
                    float zz = sigmoid2_f(aZ[r] + ZxV[r]);
                    float nn = tanh2_f(fmaf(rr, aNh[r], NiV[r]));
                    float hv = fmaf(zz, htl[r] - nn, nn);
                    hreg[r] = hv;
                    pp = fmaf(wout4[r], hv, pp);
                }
                __builtin_amdgcn_s_setprio(0);
                dcur = decN;   // dec(t+1) for next publish
                pp += __shfl_xor(pp, 16, 64);
                pp += __shfl_xor(pp, 32, 64);
                pbuf[sub] = pp;
                if (sub == 7 && l < 16) {
                    f32x4 v0 = {pbuf[0], pbuf[1], pbuf[2], pbuf[3]};
                    f32x4 v1 = {pbuf[4], pbuf[5], pbuf[6], pbuf[7]};
                    *(f32x4*)&PPc[w * 128 + n16 * 8] = v0;
                    *(f32x4*)&PPc[w * 128 + n16 * 8 + 4] = v1;
                }
            } else {
                const int tnext = tb + sub + 1;
                if (tnext < TLEN) {
                    const int parn = (tnext >> 3) & 1;
                    const int subn = tnext & 7;
                    f16x8 Bxh = *(const f16x8*)&Bx[parn * 8192 + subn * 1024 + l * 8];
                    f16x8 Bxl = *(const f16x8*)&Bx[parn * 8192 + subn * 1024 + 512 + l * 8];
                    f32x4 Rx  = MFMA(Axh[0], Bxh, zero4);
                    f32x4 Zx  = MFMA(Axh[1], Bxh, zero4);
                    f32x4 Nix = MFMA(Axh[2], Bxh, seedNi);
                    Rx  = MFMA(Axl[0], Bxh, Rx);
                    Zx  = MFMA(Axl[1], Bxh, Zx);
                    Nix = MFMA(Axl[2], Bxh, Nix);
                    Rx  = MFMA(Axh[0], Bxl, Rx);
                    Zx  = MFMA(Axh[1], Bxl, Zx);
                    Nix = MFMA(Axh[2], Bxl, Nix);
                    // dec(t+2) = dec(tb+sub+2); garbage past TLEN is never consumed
                    float dn2 = (sub == 0) ? dtc0.z : (sub == 1) ? dtc0.w
                              : (sub == 2) ? dtc1.x : (sub == 3) ? dtc1.y
                              : (sub == 4) ? dtc1.z : (sub == 5) ? dtc1.w
                              : (sub == 6) ? dtn0.x : dtn0.y;
                    f32x4 decv;
#pragma unroll
                    for (int r = 0; r < 4; ++r)
                        decv[r] = __builtin_amdgcn_exp2f(
                            -LOG2E * fmaxf(fmaf(dn2, wdt4[r], bdt4[r]), 0.f));
                    const int nb = tnext & 1;
                    *(f32x4*)&EXC[nb][p][0][l][0] = Rx;
                    *(f32x4*)&EXC[nb][p][1][l][0] = Zx;
                    *(f32x4*)&EXC[nb][p][2][l][0] = Nix;
                    *(f32x4*)&EXC[nb][p][3][l][0] = decv;
                }
                // prev-chunk output combine (PPc written at prev sub7; bar(sub0) separates)
                if (sub == 0 && tb > 0 && tid2 < 128) {
                    int b = tid2 >> 3, t8 = tid2 & 7;
                    int base = b * 8 + t8;
                    float s = PPc[base] + PPc[128 + base] + PPc[256 + base] + PPc[384 + base];
                    out[(size_t)(b0g + b) * TLEN + (tb - 8) + t8] = s + bout;
                }
                if (sub == 1 && tb + 8 < TLEN) {
#pragma unroll
                    for (int i = 0; i < 3; ++i) if (xv2[i]) xst[i] = X[xg2[i] + (tb + 8) * 5];
                }
                if (sub == 2 && tb + 8 < TLEN) {
                    dtn0 = *(const float4*)(dtb + tb + 8);
                    dtn1 = *(const float4*)(dtb + tb + 12);
                }
                // stage next chunk's x; B re-reads it first at sub7 (bars 5..7 separate)
                if (sub == 4 && tb + 8 < TLEN) {
#pragma unroll
                    for (int i = 0; i < 3; ++i) if (xv2[i]) {
                        float v = xst[i];
                        _Float16 h = (_Float16)v;
                        Bx[npar * 8192 + xw2[i]] = h;
                        Bx[npar * 8192 + 512 + xw2[i]] = (_Float16)(v - (float)h);
                    }
                }
                if (sub == 7) { dtc0 = dtn0; dtc1 = dtn1; }
            }
        }
    }

    // final chunk combine
    __syncthreads();
    if (!isA && tid2 < 128) {
        int b = tid2 >> 3, t8 = tid2 & 7;
        int base = b * 8 + t8;
        float s = PPc[base] + PPc[128 + base] + PPc[256 + base] + PPc[384 + base];
        out[(size_t)(b0g + b) * TLEN + (TLEN - 8) + t8] = s + bout;
    }
}

extern "C" void kernel_launch(void* const* d_in, const int* in_sizes, int n_in,
                              void* d_out, int out_size, void* d_ws, size_t ws_size,
                              hipStream_t stream) {
    const float* X    = (const float*)d_in[0];
    const float* dt   = (const float*)d_in[1];
    const float* w_ih = (const float*)d_in[2];
    const float* w_hh = (const float*)d_in[3];
    const float* b_ih = (const float*)d_in[4];
    const float* b_hh = (const float*)d_in[5];
    const float* w_dt = (const float*)d_in[6];
    const float* b_dt = (const float*)d_in[7];
    const float* w_out = (const float*)d_in[8];
    const float* b_out = (const float*)d_in[9];
    float* out = (float*)d_out;

    grut1_kernel<<<dim3(4096 / BT), dim3(512), 0, stream>>>(
        X, dt, w_ih, w_hh, b_ih, b_hh, w_dt, b_dt, w_out, b_out, out);
}

// Round 2
// 408.931 us; speedup vs baseline: 1.0110x; 1.0110x over previous
//
#include <hip/hip_runtime.h>
#include <math.h>

typedef _Float16 f16x8 __attribute__((ext_vector_type(8)));
typedef _Float16 f16x4 __attribute__((ext_vector_type(4)));
typedef float f32x4 __attribute__((ext_vector_type(4)));

#define TLEN 512
#define BT 16
#define MFMA(a,b,c) __builtin_amdgcn_mfma_f32_16x16x32_f16(a,b,c,0,0,0)
#define LOG2E 1.44269504f

// Workgroup barrier WITHOUT the vmcnt(0)/expcnt(0) drain __syncthreads emits.
// Only LDS data crosses the barrier (lgkmcnt(0) orders ds_writes); global
// loads are wave-private (compiler inserts vmcnt waits at use); out-stores
// are never re-read in-kernel.
__device__ __forceinline__ void bar_lds() {
    asm volatile("s_waitcnt lgkmcnt(0)\n\ts_barrier" ::: "memory");
}

__device__ __forceinline__ float sigmoid2_f(float x) {
    return __builtin_amdgcn_rcpf(1.f + __builtin_amdgcn_exp2f(-LOG2E * x));
}
__device__ __forceinline__ float tanh2_f(float x) {
    float t = __builtin_amdgcn_rcpf(1.f + __builtin_amdgcn_exp2f(2.f * LOG2E * x));
    return fmaf(-2.f, t, 1.f);
}

// R12 = R6 skeleton (4 waves, 256 thr, 1 bar/substep) + serial-chain cuts:
//  (a) x-path MFMAs (9) moved PRE-barrier; their Bx frags are read one
//      substep early (post-bar of prev iter, latency hidden under h-MFMAs),
//      so they issue stall-free in the publish->bar window. Post-bar phase
//      is 18 h-MFMAs only, starting right as the Bs read lands.
//  (b) dual accumulators per gate (dep depth 6 -> 3); gate in = a + b.
//  (c) R chains finish first (round-robin R,N,Z) so the sigmoid/tanh chain
//      overlaps the Z MFMAs; only sigma(z)+fma trail the last MFMA.
//  (d) pred shfl_xor pairs deferred to sub7 (off 7/8 of the chains).
__global__ __launch_bounds__(256, 1) void grut1_kernel(
    const float* __restrict__ X, const float* __restrict__ dtp,
    const float* __restrict__ w_ih, const float* __restrict__ w_hh,
    const float* __restrict__ b_ih, const float* __restrict__ b_hh,
    const float* __restrict__ w_dt, const float* __restrict__ b_dt,
    const float* __restrict__ w_out, const float* __restrict__ b_out,
    float* __restrict__ out)
{
    __shared__ __align__(16) _Float16 Bs[4096];    // [phase2][plane2][kt2][512]
    __shared__ __align__(16) _Float16 Bx[16384];   // [par2][t8][plane2][512]
    __shared__ __align__(16) float PPc[512];       // [wave4][b16][t8]

    const int tid = threadIdx.x;
    const int w = tid >> 6;
    const int l = tid & 63;
    const int n16 = l & 15;
    const int quad = l >> 4;
    const int b0g = blockIdx.x * BT;
    const int hq0 = w * 16 + quad * 4;

    // B-state publish offset (halfwords): k_local = 16(w&1)+4q+r, contiguous r
    const int bsoff = (w >> 1) * 512
                    + (((2 * (w & 1) + (quad >> 1)) * 16) + n16) * 8
                    + (quad & 1) * 4;

    float wdt4[4], bdt4[4], wout4[4];
    f32x4 seedR, seedZ, seedNi, biasNhV;
    const f32x4 zero4 = {0.f, 0.f, 0.f, 0.f};
#pragma unroll
    for (int r = 0; r < 4; ++r) {
        int j = hq0 + r;
        wdt4[r] = w_dt[j];
        bdt4[r] = b_dt[j];
        wout4[r] = w_out[j];
        seedR[r] = b_ih[j] + b_hh[j];
        seedZ[r] = b_ih[64 + j] + b_hh[64 + j];
        seedNi[r] = b_ih[128 + j];
        biasNhV[r] = b_hh[128 + j];
    }
    const float bout = b_out[0];

    // A-frags (weights), fp16 hi/lo, VGPR-resident. A[m=l&15][k=quad*8+j].
    f16x8 Ah[3][2], Al[3][2], Axh[3], Axl[3];
#pragma unroll
    for (int g = 0; g < 3; ++g) {
        const int row = g * 64 + w * 16 + n16;
#pragma unroll
        for (int kt = 0; kt < 2; ++kt) {
            const float* src = w_hh + row * 64 + kt * 32 + quad * 8;
            f16x8 hi, lo;
#pragma unroll
            for (int i = 0; i < 8; ++i) {
                float v = src[i];
                _Float16 h = (_Float16)v;
                hi[i] = h;
                lo[i] = (_Float16)(v - (float)h);
            }
            Ah[g][kt] = hi;
            Al[g][kt] = lo;
        }
        f16x8 hi, lo;
#pragma unroll
        for (int i = 0; i < 8; ++i) {
            float v = (quad == 0 && i < 5) ? w_ih[row * 5 + i] : 0.f;
            _Float16 h = (_Float16)v;
            hi[i] = h;
            lo[i] = (_Float16)(v - (float)h);
        }
        Axh[g] = hi;
        Axl[g] = lo;
    }

    // x staging map: v in [0,640) -> b = v/40, rem = v%40, tt = rem/5, f = rem%5
    int xg[3], xw[3], xvalid[3];
#pragma unroll
    for (int i = 0; i < 3; ++i) {
        int v = tid + i * 256;
        xvalid[i] = (v < 640);
        int vv = xvalid[i] ? v : 0;
        int b = vv / 40;
        int rem = vv - b * 40;
        int tt = rem / 5;
        int f = rem - tt * 5;
        xg[i] = (b0g + b) * (TLEN * 5) + rem;
        xw[i] = tt * 1024 + b * 8 + f;
    }

    // zero Bx (unused K slots must be 0.0f16)
    {
        float4 z4 = make_float4(0.f, 0.f, 0.f, 0.f);
        float4* p4 = (float4*)Bx;
#pragma unroll
        for (int i = 0; i < 8; ++i) p4[tid + i * 256] = z4;
    }
    __syncthreads();
    // publish chunk-0 x
#pragma unroll
    for (int i = 0; i < 3; ++i) if (xvalid[i]) {
        float v = X[xg[i]];
        _Float16 h = (_Float16)v;
        Bx[xw[i]] = h;
        Bx[512 + xw[i]] = (_Float16)(v - (float)h);
    }
    // pre-bar Bx reads in the loop require staging ordered up front
    __syncthreads();

    // pre-read sub-0 x frags
    f16x8 Bxh_c = *(const f16x8*)&Bx[l * 8];
    f16x8 Bxl_c = *(const f16x8*)&Bx[512 + l * 8];

    // chunk-0 dt (lane's batch) + dec for t=0
    const float* dtb = dtp + (size_t)(b0g + n16) * TLEN;
    float4 dtc0 = *(const float4*)(dtb);
    float4 dtc1 = *(const float4*)(dtb + 4);
    float4 dtn0, dtn1;
    float dcur[4];
#pragma unroll
    for (int r = 0; r < 4; ++r)
        dcur[r] = __builtin_amdgcn_exp2f(-LOG2E * fmaxf(fmaf(dtc0.x, wdt4[r], bdt4[r]), 0.f));

    f32x4 hreg = {0.f, 0.f, 0.f, 0.f};
    float pbuf[8];
    float xst[3];

#pragma unroll 1
    for (int tb = 0; tb < TLEN; tb += 8) {
        const int par = (tb >> 3) & 1;
        const int npar = par ^ 1;
#pragma unroll
        for (int sub = 0; sub < 8; ++sub) {
            const int pB = (sub & 1) * 2048;

            // ---- PRE-BAR: publish h~(t), stage (sub7), x-path MFMAs ----
            f32x4 htl;
            f16x4 vh, vl;
#pragma unroll
            for (int r = 0; r < 4; ++r) {
                float v = dcur[r] * hreg[r];
                htl[r] = v;
                _Float16 h = (_Float16)v;
                vh[r] = h;
                vl[r] = (_Float16)(v - (float)h);
            }
            *(f16x4*)&Bs[pB + bsoff] = vh;
            *(f16x4*)&Bs[pB + 1024 + bsoff] = vl;
            if (sub == 7 && tb + 8 < TLEN) {
                // publish next chunk's x-frags
#pragma unroll
                for (int i = 0; i < 3; ++i) if (xvalid[i]) {
                    float v = xst[i];
                    _Float16 h = (_Float16)v;
                    Bx[npar * 8192 + xw[i]] = h;
                    Bx[npar * 8192 + 512 + xw[i]] = (_Float16)(v - (float)h);
                }
            }
            // 9 x-path MFMAs for t (frags pre-read -> zero LDS stall),
            // bias-seeded; results are the C-seeds of the post-bar chains.
            f32x4 xR  = MFMA(Axh[0], Bxh_c, seedR);
            f32x4 xZ  = MFMA(Axh[1], Bxh_c, seedZ);
            f32x4 xNi = MFMA(Axh[2], Bxh_c, seedNi);
            xR  = MFMA(Axl[0], Bxh_c, xR);
            xZ  = MFMA(Axl[1], Bxh_c, xZ);
            xNi = MFMA(Axl[2], Bxh_c, xNi);
            xR  = MFMA(Axh[0], Bxl_c, xR);
            xZ  = MFMA(Axh[1], Bxl_c, xZ);
            xNi = MFMA(Axh[2], Bxl_c, xNi);

            bar_lds();   // lgkmcnt(0) + s_barrier only -- NO vmcnt drain

            // ---- POST-BAR ----
            f16x8 Bh0 = *(const f16x8*)&Bs[pB + l * 8];
            f16x8 Bh1 = *(const f16x8*)&Bs[pB + 512 + l * 8];
            f16x8 Bl0 = *(const f16x8*)&Bs[pB + 1024 + l * 8];
            f16x8 Bl1 = *(const f16x8*)&Bs[pB + 1536 + l * 8];
            // prefetch NEXT substep's x frags (latency hidden under h-MFMAs).
            // At sub7 this reads Bx[npar], staged pre-bar and ordered by the
            // barrier just crossed. Last-chunk sub7 reads stale data, unused.
            const int nspar = (sub == 7) ? npar : par;
            const int nsub = (sub + 1) & 7;
            f16x8 Bxh_n = *(const f16x8*)&Bx[nspar * 8192 + nsub * 1024 + l * 8];
            f16x8 Bxl_n = *(const f16x8*)&Bx[nspar * 8192 + nsub * 1024 + 512 + l * 8];

            // prev-chunk output combine (piggybacks on this barrier)
            if (sub == 0 && tb > 0 && tid < 128) {
                int b = tid >> 3, t8 = tid & 7;
                int base = b * 8 + t8;
                float s = PPc[base] + PPc[128 + base] + PPc[256 + base] + PPc[384 + base];
                out[(size_t)(b0g + b) * TLEN + (tb - 8) + t8] = s + bout;
            }
            // next-chunk prefetches (latency covered until consumed; no drains)
            if (sub == 1 && tb + 8 < TLEN) {
#pragma unroll
                for (int i = 0; i < 3; ++i) if (xvalid[i]) xst[i] = X[xg[i] + (tb + 8) * 5];
            }
            if (sub == 2 && tb + 8 < TLEN) {
                dtn0 = *(const float4*)(dtb + tb + 8);
                dtn1 = *(const float4*)(dtb + tb + 12);
            }

            // ---- 18 h-MFMAs: 6 chains of depth 3, R-first round-robin ----
            f32x4 aRa = MFMA(Ah[0][0], Bh0, xR);
            f32x4 aRb = MFMA(Ah[0][1], Bh1, zero4);
            f32x4 aNa = MFMA(Ah[2][0], Bh0, biasNhV);
            f32x4 aNb = MFMA(Ah[2][1], Bh1, zero4);
            f32x4 aZa = MFMA(Ah[1][0], Bh0, xZ);
            f32x4 aZb = MFMA(Ah[1][1], Bh1, zero4);
            aRa = MFMA(Al[0][0], Bh0, aRa);
            aRb = MFMA(Al[0][1], Bh1, aRb);
            aNa = MFMA(Al[2][0], Bh0, aNa);
            aNb = MFMA(Al[2][1], Bh1, aNb);
            aZa = MFMA(Al[1][0], Bh0, aZa);
            aZb = MFMA(Al[1][1], Bh1, aZb);
            aRa = MFMA(Ah[0][0], Bl0, aRa);
            aRb = MFMA(Ah[0][1], Bl1, aRb);
            aNa = MFMA(Ah[2][0], Bl0, aNa);
            aNb = MFMA(Ah[2][1], Bl1, aNb);
            aZa = MFMA(Ah[1][0], Bl0, aZa);
            aZb = MFMA(Ah[1][1], Bl1, aZb);

            // dec for t+1 (under MFMA shadow)
            if (tb + 8 < TLEN || sub < 7) {
                float dnext = (sub == 0) ? dtc0.y : (sub == 1) ? dtc0.z : (sub == 2) ? dtc0.w
                            : (sub == 3) ? dtc1.x : (sub == 4) ? dtc1.y : (sub == 5) ? dtc1.z
                            : (sub == 6) ? dtc1.w : dtn0.x;
#pragma unroll
                for (int r = 0; r < 4; ++r)
                    dcur[r] = __builtin_amdgcn_exp2f(-LOG2E * fmaxf(fmaf(dnext, wdt4[r], bdt4[r]), 0.f));
            }

            // ---- gates + h update + lane-partial pred ----
            float p = 0.f;
#pragma unroll
            for (int r = 0; r < 4; ++r) {
                float rr = sigmoid2_f(aRa[r] + aRb[r]);
                float zz = sigmoid2_f(aZa[r] + aZb[r]);
                float nn = tanh2_f(fmaf(rr, aNa[r] + aNb[r], xNi[r]));
                float hv = fmaf(zz, htl[r] - nn, nn);
                hreg[r] = hv;
                p = fmaf(wout4[r], hv, p);
            }
            pbuf[sub] = p;

            if (sub == 7) {
                // deferred pred reductions for the whole chunk
#pragma unroll
                for (int s = 0; s < 8; ++s) {
                    pbuf[s] += __shfl_xor(pbuf[s], 16, 64);
                    pbuf[s] += __shfl_xor(pbuf[s], 32, 64);
                }
                if (l < 16) {
                    f32x4 v0 = {pbuf[0], pbuf[1], pbuf[2], pbuf[3]};
                    f32x4 v1 = {pbuf[4], pbuf[5], pbuf[6], pbuf[7]};
                    *(f32x4*)&PPc[w * 128 + n16 * 8] = v0;
                    *(f32x4*)&PPc[w * 128 + n16 * 8 + 4] = v1;
                }
                dtc0 = dtn0;
                dtc1 = dtn1;
            }
            Bxh_c = Bxh_n;
            Bxl_c = Bxl_n;
        }
    }

    // final chunk combine
    __syncthreads();
    if (tid < 128) {
        int b = tid >> 3, t8 = tid & 7;
        int base = b * 8 + t8;
        float s = PPc[base] + PPc[128 + base] + PPc[256 + base] + PPc[384 + base];
        out[(size_t)(b0g + b) * TLEN + (TLEN - 8) + t8] = s + bout;
    }
}

extern "C" void kernel_launch(void* const* d_in, const int* in_sizes, int n_in,
                              void* d_out, int out_size, void* d_ws, size_t ws_size,
                              hipStream_t stream) {
    const float* X    = (const float*)d_in[0];
    const float* dt   = (const float*)d_in[1];
    const float* w_ih = (const float*)d_in[2];
    const float* w_hh = (const float*)d_in[3];
    const float* b_ih = (const float*)d_in[4];
    const float* b_hh = (const float*)d_in[5];
    const float* w_dt = (const float*)d_in[6];
    const float* b_dt = (const float*)d_in[7];
    const float* w_out = (const float*)d_in[8];
    const float* b_out = (const float*)d_in[9];
    float* out = (float*)d_out;

    grut1_kernel<<<dim3(4096 / BT), dim3(256), 0, stream>>>(
        X, dt, w_ih, w_hh, b_ih, b_hh, w_dt, b_dt, w_out, b_out, out);
}